// Round 4
// baseline (1526.537 us; speedup 1.0000x reference)
//
#include <hip/hip_runtime.h>
#include <hip/hip_bf16.h>

#define DEV __device__ __forceinline__

namespace {

constexpr int cB = 2, cT = 8, cH = 32, cW = 32, cC = 192;
constexpr int cDI = 384, cN = 16, cK = 4, cDTR = 12, cLT = 77, cHID = 768;
constexpr int cL  = cT * cH * cW;      // 8192
constexpr int cBL = cB * cL;           // 16384
constexpr int SEG = 64, SEGLEN = cL / SEG;   // 64 segments x 128 steps
constexpr int XROW = cDTR + 2 * cN;    // 44 = dtr(12) + B(16) + C(16)

// ---------- scalar helpers ----------
DEV float bfu2f(unsigned short u) { return __uint_as_float(((unsigned)u) << 16); }
// dtype-flagged load: f32 != 0 -> fp32 buffer, else bf16 buffer
DEV float ldsel(const void* p, size_t i, int f32) {
  return f32 ? ((const float*)p)[i] : bfu2f(((const unsigned short*)p)[i]);
}
DEV float siluf(float x) { return x / (1.f + __expf(-x)); }
DEV float softplusf(float x) { return (x > 20.f) ? x : log1pf(__expf(x)); }
DEV float gelut(float x) {            // tanh-approx gelu (JAX default)
  float u = 0.7978845608028654f * (x + 0.044715f * x * x * x);
  float e = __expf(2.f * u);
  float th = 1.f - 2.f / (e + 1.f);   // robust tanh (no inf/inf)
  return 0.5f * x * (1.f + th);
}

template <int BS>
DEV void blkreduce2(float& a, float& b) {
  __shared__ float ra[BS], rb[BS];
  int t = threadIdx.x;
  ra[t] = a; rb[t] = b; __syncthreads();
#pragma unroll
  for (int s = BS / 2; s > 0; s >>= 1) {
    if (t < s) { ra[t] += ra[t + s]; rb[t] += rb[t + s]; }
    __syncthreads();
  }
  a = ra[0]; b = rb[0];
  __syncthreads();
}

// ---------- dtype detector ----------
// Examines even-indexed ushorts: for a bf16 tensor these are real values
// (~100% plausible); for an fp32 tensor they are low mantissa halves
// (~16% plausible). flg[0]=activations fp32?, flg[1]=params fp32?, flg[2]=1.
__global__ void __launch_bounds__(256) detect_kernel(
    const unsigned short* __restrict__ xa, const unsigned short* __restrict__ wp,
    int* __restrict__ flg) {
  __shared__ int cnt[2];
  if (threadIdx.x < 2) cnt[threadIdx.x] = 0;
  __syncthreads();
  int l0 = 0, l1 = 0;
  for (int i = threadIdx.x; i < 1024; i += 256) {
    float v = bfu2f(xa[2 * i]); float a = fabsf(v);
    if (v == 0.f || (a > 1e-8f && a < 1e4f)) l0++;
    float u = bfu2f(wp[2 * i]); float bq = fabsf(u);
    if (u == 0.f || (bq > 1e-8f && bq < 1e4f)) l1++;
  }
  atomicAdd(&cnt[0], l0); atomicAdd(&cnt[1], l1);
  __syncthreads();
  if (threadIdx.x == 0) {
    flg[0] = (cnt[0] < 614) ? 1 : 0;
    flg[1] = (cnt[1] < 614) ? 1 : 0;
    flg[2] = 1;
  }
}

// ---------- zero-fill ----------
__global__ void __launch_bounds__(256) zero4_kernel(float4* __restrict__ p, int n4) {
  int i = blockIdx.x * 256 + threadIdx.x;
  if (i < n4) p[i] = make_float4(0.f, 0.f, 0.f, 0.f);
}

// ---------- depthwise 3x3x3 conv + residual (CPE), channels-last ----------
// xin dtype selected by flg[afidx] (fp32 ws passes afidx=2 -> always fp32).
__global__ void __launch_bounds__(256) cpe_kernel(
    const void* __restrict__ xin, const void* __restrict__ w27,
    const void* __restrict__ bias, const int* __restrict__ flg, int afidx,
    float* __restrict__ out) {
  int af = flg[afidx], pf = flg[1];
  int idx = blockIdx.x * 256 + threadIdx.x;
  if (idx >= cBL * cC) return;
  int c = idx % cC; int bv = idx / cC;
  int v = bv & (cL - 1); int b = bv >> 13;
  int t = v >> 10, q = v & 1023, h = q >> 5, w = q & 31;
  float acc = ldsel(bias, c, pf);
#pragma unroll
  for (int dz = 0; dz < 3; ++dz) {
    int tt = t + dz - 1; if ((unsigned)tt >= (unsigned)cT) continue;
#pragma unroll
    for (int dy = 0; dy < 3; ++dy) {
      int hh = h + dy - 1; if ((unsigned)hh >= (unsigned)cH) continue;
#pragma unroll
      for (int dx = 0; dx < 3; ++dx) {
        int ww = w + dx - 1; if ((unsigned)ww >= (unsigned)cW) continue;
        int vv = (tt << 10) + (hh << 5) + ww;
        acc += ldsel(w27, c * 27 + dz * 9 + dy * 3 + dx, pf) *
               ldsel(xin, ((size_t)b * cL + vv) * cC + c, af);
      }
    }
  }
  out[idx] = ldsel(xin, idx, af) + acc;
}

// ---------- depthwise conv on DI channels + SiLU (ws fp32 input) ----------
__global__ void __launch_bounds__(256) dwconv_silu_kernel(
    const float* __restrict__ xin, const void* __restrict__ w27,
    const void* __restrict__ bias, const int* __restrict__ flg,
    float* __restrict__ out) {
  int pf = flg[1];
  int idx = blockIdx.x * 256 + threadIdx.x;
  if (idx >= cBL * cDI) return;
  int d = idx % cDI; int bv = idx / cDI;
  int v = bv & (cL - 1); int b = bv >> 13;
  int t = v >> 10, q = v & 1023, h = q >> 5, w = q & 31;
  float acc = ldsel(bias, d, pf);
#pragma unroll
  for (int dz = 0; dz < 3; ++dz) {
    int tt = t + dz - 1; if ((unsigned)tt >= (unsigned)cT) continue;
#pragma unroll
    for (int dy = 0; dy < 3; ++dy) {
      int hh = h + dy - 1; if ((unsigned)hh >= (unsigned)cH) continue;
#pragma unroll
      for (int dx = 0; dx < 3; ++dx) {
        int ww = w + dx - 1; if ((unsigned)ww >= (unsigned)cW) continue;
        int vv = (tt << 10) + (hh << 5) + ww;
        acc += ldsel(w27, d * 27 + dz * 9 + dy * 3 + dx, pf) *
               xin[((size_t)b * cL + vv) * cDI + d];
      }
    }
  }
  out[idx] = siluf(acc);
}

// ---------- row LayerNorm (fp32 ws in/out, flagged gamma/beta) ----------
__global__ void __launch_bounds__(256) ln_kernel(
    const float* __restrict__ in, const void* __restrict__ g,
    const void* __restrict__ bb, const int* __restrict__ flg,
    float* __restrict__ out, int D) {
  int pf = flg[1];
  int row = blockIdx.x;
  const float* x = in + (size_t)row * D;
  float s1 = 0.f, s2 = 0.f;
  for (int i = threadIdx.x; i < D; i += 256) { float v = x[i]; s1 += v; s2 += v * v; }
  blkreduce2<256>(s1, s2);
  float mean = s1 / D;
  float var = s2 / D - mean * mean;
  float rstd = rsqrtf(var + 1e-6f);
  float* o = out + (size_t)row * D;
  for (int i = threadIdx.x; i < D; i += 256)
    o[i] = (x[i] - mean) * rstd * ldsel(g, i, pf) + ldsel(bb, i, pf);
}

// ---------- text conditioning: silu(mean_t(text) @ Wt^T + bt) ----------
__global__ void __launch_bounds__(384) text_cond_kernel(
    const void* __restrict__ text, const void* __restrict__ tw,
    const void* __restrict__ tb, const int* __restrict__ flg,
    float* __restrict__ cond) {
  int af = flg[0], pf = flg[1];
  __shared__ float mean[cC];
  int b = blockIdx.x;
  for (int c = threadIdx.x; c < cC; c += 384) {
    float s = 0.f;
    for (int t = 0; t < cLT; ++t) s += ldsel(text, ((size_t)b * cLT + t) * cC + c, af);
    mean[c] = s * (1.f / cLT);
  }
  __syncthreads();
  int di = threadIdx.x;
  float a = ldsel(tb, di, pf);
  for (int c = 0; c < cC; ++c) a += mean[c] * ldsel(tw, di * cC + c, pf);
  cond[b * cDI + di] = siluf(a);
}

// ---------- generic tiled GEMM: out = epilogue(A[M,K] @ W[N,K]^T) ----------
// MODE 0: in_proj  -> xi (+bias+cond) / z (+bias)
// MODE 1: x_proj   -> scatter into xdbl[b,k,l,44] by cross-scan position
// MODE 2: out_proj -> x2 = acc + x1
// MODE 3: fc1      -> hbuf = gelu(acc + bias)
// MODE 4: fc2      -> out(fp32) = acc + bias + x3   (d_out is float: ref output dtype)
template <int MODE>
__global__ void __launch_bounds__(256) gemm_kernel(
    const float* __restrict__ A, const void* __restrict__ W,
    int N, int K, const void* __restrict__ bias, const int* __restrict__ flg,
    const float* __restrict__ extra, float* __restrict__ out,
    float* __restrict__ out2) {
  int pf = flg[1];
  constexpr int BM = 64, BN = 64, BK = 16;
  __shared__ float As[BK][BM + 4];   // [k][m], 272B rows keep 16B align
  __shared__ float Bs[BK][BN + 4];   // [k][n]
  int tid = threadIdx.x;
  int tx = tid & 15, ty = tid >> 4;
  int m0 = blockIdx.y * BM, n0 = blockIdx.x * BN;
  int lrow = tid >> 2, lc = (tid & 3) * 4;
  float acc[4][4] = {};
  for (int k0 = 0; k0 < K; k0 += BK) {
    float4 av = *(const float4*)(A + (size_t)(m0 + lrow) * K + k0 + lc);
    As[lc + 0][lrow] = av.x; As[lc + 1][lrow] = av.y;
    As[lc + 2][lrow] = av.z; As[lc + 3][lrow] = av.w;
    float b0 = 0.f, b1 = 0.f, b2 = 0.f, b3 = 0.f;
    int nr = n0 + lrow;
    if (nr < N) {
      size_t wi = (size_t)nr * K + k0 + lc;
      if (pf) {
        float4 wv = *(const float4*)((const float*)W + wi);
        b0 = wv.x; b1 = wv.y; b2 = wv.z; b3 = wv.w;
      } else {
        ushort4 wv = *(const ushort4*)((const unsigned short*)W + wi);
        b0 = bfu2f(wv.x); b1 = bfu2f(wv.y); b2 = bfu2f(wv.z); b3 = bfu2f(wv.w);
      }
    }
    Bs[lc + 0][lrow] = b0; Bs[lc + 1][lrow] = b1;
    Bs[lc + 2][lrow] = b2; Bs[lc + 3][lrow] = b3;
    __syncthreads();
#pragma unroll
    for (int kk = 0; kk < BK; ++kk) {
      float4 a4 = *(const float4*)(&As[kk][ty * 4]);
      float4 b4 = *(const float4*)(&Bs[kk][tx * 4]);
      acc[0][0] += a4.x * b4.x; acc[0][1] += a4.x * b4.y; acc[0][2] += a4.x * b4.z; acc[0][3] += a4.x * b4.w;
      acc[1][0] += a4.y * b4.x; acc[1][1] += a4.y * b4.y; acc[1][2] += a4.y * b4.z; acc[1][3] += a4.y * b4.w;
      acc[2][0] += a4.z * b4.x; acc[2][1] += a4.z * b4.y; acc[2][2] += a4.z * b4.z; acc[2][3] += a4.z * b4.w;
      acc[3][0] += a4.w * b4.x; acc[3][1] += a4.w * b4.y; acc[3][2] += a4.w * b4.z; acc[3][3] += a4.w * b4.w;
    }
    __syncthreads();
  }
#pragma unroll
  for (int i = 0; i < 4; ++i) {
    int m = m0 + ty * 4 + i;
#pragma unroll
    for (int j = 0; j < 4; ++j) {
      int n = n0 + tx * 4 + j;
      float v = acc[i][j];
      if (MODE == 0) {
        float bv = ldsel(bias, n, pf);
        int b = m >> 13;
        if (n < cDI) out[(size_t)m * cDI + n] = v + bv + extra[b * cDI + n];
        else         out2[(size_t)m * cDI + (n - cDI)] = v + bv;
      } else if (MODE == 1) {
        if (n < cK * XROW) {
          int k = n / XROW, c = n - k * XROW;
          int b = m >> 13, vv = m & (cL - 1);
          int t = vv >> 10, q = vv & 1023, h = q >> 5, w = q & 31;
          int l1 = (t << 10) + (w << 5) + h;
          int lk = (k == 0) ? vv : (k == 1) ? l1 : (k == 2) ? (cL - 1 - vv) : (cL - 1 - l1);
          out[((size_t)(b * cK + k) * cL + lk) * XROW + c] = v;
        }
      } else if (MODE == 2) {
        out[(size_t)m * cC + n] = v + extra[(size_t)m * cC + n];
      } else if (MODE == 3) {
        out[(size_t)m * cHID + n] = gelut(v + ldsel(bias, n, pf));
      } else {
        out[(size_t)m * cC + n] = v + ldsel(bias, n, pf) + extra[(size_t)m * cC + n];
      }
    }
  }
}

// voxel index for scan position l in direction k
DEV int scan_voxel(int k, int l) {
  if (k == 0) return l;
  if (k == 2) return cL - 1 - l;
  int ll = (k == 1) ? l : (cL - 1 - l);
  int t = ll >> 10, q = ll & 1023, w = q >> 5, h = q & 31;  // dir1 enumerates (t,w,h)
  return (t << 10) + (h << 5) + w;
}

// ---------- scan pass 1: per-segment local scan (h0=0) ----------
__global__ void __launch_bounds__(128) scan1_kernel(
    const float* __restrict__ xc, const float* __restrict__ xdbl,
    const void* __restrict__ dtw, const void* __restrict__ dtbv,
    const void* __restrict__ alog, const void* __restrict__ dsv,
    const int* __restrict__ flg,
    float* __restrict__ ysm, float* __restrict__ hend, float* __restrict__ pend) {
  int pf = flg[1];
  int d = blockIdx.x * 128 + threadIdx.x;
  int bks = blockIdx.y;
  int s = bks & (SEG - 1); int bk = bks >> 6; int k = bk & 3; int b = bk >> 2;
  float wdt[cDTR];
#pragma unroll
  for (int r = 0; r < cDTR; ++r) wdt[r] = ldsel(dtw, (size_t)(k * cDI + d) * cDTR + r, pf);
  float dtb = ldsel(dtbv, k * cDI + d, pf);
  float ac[cN];
#pragma unroll
  for (int n = 0; n < cN; ++n)
    ac[n] = -__expf(ldsel(alog, (size_t)(k * cDI + d) * cN + n, pf)) * 1.4426950408889634f;
  float Dsd = ldsel(dsv, k * cDI + d, pf);
  float h[cN], P[cN];
#pragma unroll
  for (int n = 0; n < cN; ++n) { h[n] = 0.f; P[n] = 1.f; }
  const float* xrow = xdbl + (size_t)bk * cL * XROW;
  int l0 = s * SEGLEN;
  for (int st = 0; st < SEGLEN; ++st) {
    int l = l0 + st;
    const float* rr = xrow + (size_t)l * XROW;   // wave-uniform row
    float draw = dtb;
#pragma unroll
    for (int r = 0; r < cDTR; ++r) draw += rr[r] * wdt[r];
    float dt = softplusf(draw);
    int v = scan_voxel(k, l);
    float u = xc[((size_t)b * cL + v) * cDI + d];
    float dtu = dt * u;
    float y = Dsd * u;
#pragma unroll
    for (int n = 0; n < cN; ++n) {
      float a = exp2f(dt * ac[n]);
      h[n] = h[n] * a + dtu * rr[cDTR + n];
      P[n] *= a;
      y += h[n] * rr[cDTR + cN + n];
    }
    atomicAdd(&ysm[((size_t)b * cL + v) * cDI + d], y);
  }
  size_t so = ((size_t)bks * cDI + d) * cN;
#pragma unroll
  for (int n = 0; n < cN; ++n) { hend[so + n] = h[n]; pend[so + n] = P[n]; }
}

// ---------- scan pass 2: inter-segment recurrence (hin in-place over hend) ----------
__global__ void __launch_bounds__(256) scan2_kernel(
    float* __restrict__ hend, const float* __restrict__ pend) {
  int tid = blockIdx.x * 256 + threadIdx.x;   // B*K*DI*N = 49152
  int bk = tid / (cDI * cN); int r = tid - bk * (cDI * cN);
  float g = 0.f;
  for (int s = 0; s < SEG; ++s) {
    size_t o = ((size_t)(bk * SEG + s) * cDI * cN) + r;
    float he = hend[o], pe = pend[o];
    hend[o] = g;                 // h_in for this segment
    g = pe * g + he;
  }
}

// ---------- scan pass 3: replay decay from h_in, add C.(P_l*h_in) into ysm ----------
__global__ void __launch_bounds__(128) scan3_kernel(
    const float* __restrict__ xdbl,
    const void* __restrict__ dtw, const void* __restrict__ dtbv,
    const void* __restrict__ alog, const int* __restrict__ flg,
    const float* __restrict__ hin, float* __restrict__ ysm) {
  int bks = blockIdx.y;
  int s = bks & (SEG - 1);
  if (s == 0) return;                 // h_in = 0 contributes nothing
  int pf = flg[1];
  int d = blockIdx.x * 128 + threadIdx.x;
  int bk = bks >> 6; int k = bk & 3; int b = bk >> 2;
  float wdt[cDTR];
#pragma unroll
  for (int r = 0; r < cDTR; ++r) wdt[r] = ldsel(dtw, (size_t)(k * cDI + d) * cDTR + r, pf);
  float dtb = ldsel(dtbv, k * cDI + d, pf);
  float ac[cN];
#pragma unroll
  for (int n = 0; n < cN; ++n)
    ac[n] = -__expf(ldsel(alog, (size_t)(k * cDI + d) * cN + n, pf)) * 1.4426950408889634f;
  float g[cN];
  size_t so = ((size_t)bks * cDI + d) * cN;
#pragma unroll
  for (int n = 0; n < cN; ++n) g[n] = hin[so + n];
  const float* xrow = xdbl + (size_t)bk * cL * XROW;
  int l0 = s * SEGLEN;
  for (int st = 0; st < SEGLEN; ++st) {
    int l = l0 + st;
    const float* rr = xrow + (size_t)l * XROW;
    float draw = dtb;
#pragma unroll
    for (int r = 0; r < cDTR; ++r) draw += rr[r] * wdt[r];
    float dt = softplusf(draw);
    float y = 0.f;
#pragma unroll
    for (int n = 0; n < cN; ++n) {
      float a = exp2f(dt * ac[n]);
      g[n] *= a;
      y += g[n] * rr[cDTR + cN + n];
    }
    int v = scan_voxel(k, l);
    atomicAdd(&ysm[((size_t)b * cL + v) * cDI + d], y);
  }
}

// ---------- out_norm LN over merged ysm + silu(z) gate (yg in-place over z) ----------
__global__ void __launch_bounds__(128) merge_kernel(
    const float* __restrict__ ysm, const float* __restrict__ z,
    const void* __restrict__ ong, const void* __restrict__ onb,
    const int* __restrict__ flg, float* __restrict__ yg) {
  int pf = flg[1];
  int bv = blockIdx.x;
  const float* yr = ysm + (size_t)bv * cDI;
  float vals[3]; float s1 = 0.f, s2 = 0.f;
#pragma unroll
  for (int i = 0; i < 3; ++i) {
    int d = threadIdx.x + i * 128;
    float x = yr[d];
    vals[i] = x; s1 += x; s2 += x * x;
  }
  blkreduce2<128>(s1, s2);
  float mean = s1 * (1.f / cDI);
  float var = s2 * (1.f / cDI) - mean * mean;
  float rstd = rsqrtf(var + 1e-6f);
  const float* zr = z + (size_t)bv * cDI;
  float* og = yg + (size_t)bv * cDI;
#pragma unroll
  for (int i = 0; i < 3; ++i) {
    int d = threadIdx.x + i * 128;
    float xn = (vals[i] - mean) * rstd * ldsel(ong, d, pf) + ldsel(onb, d, pf);
    og[d] = xn * siluf(zr[d]);
  }
}

}  // namespace

extern "C" void kernel_launch(void* const* d_in, const int* in_sizes, int n_in,
                              void* d_out, int out_size, void* d_ws, size_t ws_size,
                              hipStream_t stream) {
  (void)in_sizes; (void)n_in; (void)out_size; (void)ws_size;
  const void* x    = d_in[0];
  const void* text = d_in[1];
  const void* c1w  = d_in[2];
  const void* c1b  = d_in[3];
  const void* c2w  = d_in[4];
  const void* c2b  = d_in[5];
  const void* n1g  = d_in[6];
  const void* n1b  = d_in[7];
  const void* n2g  = d_in[8];
  const void* n2b  = d_in[9];
  const void* ipw  = d_in[10];
  const void* ipb  = d_in[11];
  const void* tpw  = d_in[12];
  const void* tpb  = d_in[13];
  const void* cvw  = d_in[14];
  const void* cvb  = d_in[15];
  const void* xpw  = d_in[16];
  const void* dtw  = d_in[17];
  const void* dtb  = d_in[18];
  const void* alog = d_in[19];
  const void* dsv  = d_in[20];
  const void* ong  = d_in[21];
  const void* onb  = d_in[22];
  const void* opw  = d_in[23];
  const void* f1w  = d_in[24];
  const void* f1b  = d_in[25];
  const void* f2w  = d_in[26];
  const void* f2b  = d_in[27];

  float* Wf = (float*)d_ws;

  // ---- slot-based arena, ~124.8 MB; liveness audited (rounds 1-3) ----
  constexpr size_t oC  = 0;                              // 6,291,456
  constexpr size_t oD  = 6291456;                        // 2,883,584
  constexpr size_t oG  = 9175040;                        // 3,145,728
  constexpr size_t oA  = 12320768;                       // 6,291,456
  constexpr size_t oB  = 18612224;                       // 6,291,456
  constexpr size_t oE  = 24903680;                       // 3,145,728
  constexpr size_t oF  = 28049408;                       // 3,145,728
  constexpr size_t oCO = 31195136;                       // 768 (cond)
  constexpr size_t oFL = 31195904;                       // 4 ints (flags)
  float* xc   = Wf + oC;
  float* xdbl = Wf + oD;
  float* xn   = Wf + oG;   // LN1 out
  float* pend = Wf + oG;   // after xn dead
  float* xi   = Wf + oA;
  float* ysm  = Wf + oA;   // after xi dead (zero-filled first)
  float* x2   = Wf + oA;   // after ysm dead
  float* z    = Wf + oB;
  float* yg   = Wf + oB;   // in-place gate output
  float* x3   = Wf + oB;   // after yg dead
  float* x1   = Wf + oE;
  float* hend = Wf + oF;   // becomes hin in-place (scan2)
  float* xn2  = Wf + oF;   // after hin dead
  float* cond = Wf + oCO;
  float* hbuf = Wf + oC;   // 12.58M floats over C+D+G+head-of-A (all dead by fc1)
  int*   flg  = (int*)(Wf + oFL);

  const int eltBlocksC  = (cBL * cC + 255) / 256;
  const int eltBlocksDI = (cBL * cDI + 255) / 256;

  // 0. dtype detection (activations from x, params from in_proj_w)
  hipLaunchKernelGGL(detect_kernel, dim3(1), dim3(256), 0, stream,
                     (const unsigned short*)x, (const unsigned short*)ipw, flg);
  // 1. x1 = x + cpe1(x)
  hipLaunchKernelGGL(cpe_kernel, dim3(eltBlocksC), dim3(256), 0, stream,
                     x, c1w, c1b, flg, 0, x1);
  // 2. xn = LN1(x1)
  hipLaunchKernelGGL(ln_kernel, dim3(cBL), dim3(256), 0, stream, x1, n1g, n1b, flg, xn, cC);
  // 3. cond = silu(mean(text) @ tpw^T + tpb)
  hipLaunchKernelGGL(text_cond_kernel, dim3(cB), dim3(384), 0, stream, text, tpw, tpb, flg, cond);
  // 4. in_proj: xn -> xi (+cond), z
  hipLaunchKernelGGL((gemm_kernel<0>), dim3(2 * cDI / 64, cBL / 64), dim3(256), 0, stream,
                     xn, ipw, 2 * cDI, cC, ipb, flg, cond, xi, z);
  // 5. xc = silu(dwconv(xi))   [xi dead after this]
  hipLaunchKernelGGL(dwconv_silu_kernel, dim3(eltBlocksDI), dim3(256), 0, stream,
                     xi, cvw, cvb, flg, xc);
  // 6. zero ysm (slot A, reusing xi's storage)
  hipLaunchKernelGGL(zero4_kernel, dim3(cBL * cDI / 4 / 256), dim3(256), 0, stream,
                     (float4*)ysm, cBL * cDI / 4);
  // 7. x_proj (4 directions fused, scatter to scan order)
  hipLaunchKernelGGL((gemm_kernel<1>), dim3((cK * XROW + 63) / 64, cBL / 64), dim3(256), 0, stream,
                     xc, xpw, cK * XROW, cDI, (const void*)nullptr, flg,
                     (const float*)nullptr, xdbl, (float*)nullptr);
  // 8-10. chunked selective scan (atomic accumulate into merged voxel-order ysm)
  hipLaunchKernelGGL(scan1_kernel, dim3(cDI / 128, cB * cK * SEG), dim3(128), 0, stream,
                     xc, xdbl, dtw, dtb, alog, dsv, flg, ysm, hend, pend);
  hipLaunchKernelGGL(scan2_kernel, dim3(cB * cK * cDI * cN / 256), dim3(256), 0, stream,
                     hend, pend);
  hipLaunchKernelGGL(scan3_kernel, dim3(cDI / 128, cB * cK * SEG), dim3(128), 0, stream,
                     xdbl, dtw, dtb, alog, flg, hend, ysm);
  // 11. out_norm + gate -> yg (in-place over z)
  hipLaunchKernelGGL(merge_kernel, dim3(cBL), dim3(128), 0, stream, ysm, z, ong, onb, flg, yg);
  // 12. out_proj + residual(x1) -> x2 (slot A; ysm dead)
  hipLaunchKernelGGL((gemm_kernel<2>), dim3(cC / 64, cBL / 64), dim3(256), 0, stream,
                     yg, opw, cC, cDI, (const void*)nullptr, flg, x1, x2,
                     (float*)nullptr);
  // 13. x3 = x2 + cpe2(x2)  (slot B; yg dead) — afidx=2 forces fp32 input
  hipLaunchKernelGGL(cpe_kernel, dim3(eltBlocksC), dim3(256), 0, stream,
                     x2, c2w, c2b, flg, 2, x3);
  // 14. xn2 = LN2(x3)  (slot F; hin dead)
  hipLaunchKernelGGL(ln_kernel, dim3(cBL), dim3(256), 0, stream, x3, n2g, n2b, flg, xn2, cC);
  // 15. fc1 + gelu -> hbuf  (slots C/D/G + head of A; all dead)
  hipLaunchKernelGGL((gemm_kernel<3>), dim3(cHID / 64, cBL / 64), dim3(256), 0, stream,
                     xn2, f1w, cHID, cC, f1b, flg, (const float*)nullptr, hbuf,
                     (float*)nullptr);
  // 16. fc2 + bias + residual(x3) -> out (fp32, reference output dtype)
  hipLaunchKernelGGL((gemm_kernel<4>), dim3(cC / 64, cBL / 64), dim3(256), 0, stream,
                     hbuf, f2w, cC, cHID, f2b, flg, x3, (float*)d_out,
                     (float*)nullptr);
}

// Round 5
// 1034.761 us; speedup vs baseline: 1.4753x; 1.4753x over previous
//
#include <hip/hip_runtime.h>
#include <hip/hip_bf16.h>

#define DEV __device__ __forceinline__

namespace {

constexpr int cB = 2, cT = 8, cH = 32, cW = 32, cC = 192;
constexpr int cDI = 384, cN = 16, cK = 4, cDTR = 12, cLT = 77, cHID = 768;
constexpr int cL  = cT * cH * cW;      // 8192
constexpr int cBL = cB * cL;           // 16384
constexpr int SEG = 64, SEGLEN = cL / SEG;   // 64 segments x 128 steps
constexpr int XROW = cDTR + 2 * cN;    // 44 live cols
constexpr int XSTR = 48;               // padded row stride (float4-aligned)

typedef __attribute__((ext_vector_type(8))) short bf16x8;
typedef __attribute__((ext_vector_type(4))) float f32x4;
typedef __attribute__((ext_vector_type(4))) short short4v;

// ---------- scalar helpers ----------
DEV float bfu2f(unsigned short u) { return __uint_as_float(((unsigned)u) << 16); }
DEV float ldsel(const void* p, size_t i, int f32) {
  return f32 ? ((const float*)p)[i] : bfu2f(((const unsigned short*)p)[i]);
}
DEV short f2bf(float f) {   // RNE float->bf16 bits
  unsigned u = __float_as_uint(f);
  u += 0x7fffu + ((u >> 16) & 1u);
  return (short)(u >> 16);
}
DEV float siluf(float x) { return x / (1.f + __expf(-x)); }
DEV float softplusf(float x) { return (x > 20.f) ? x : __logf(1.f + __expf(x)); }
DEV float gelut(float x) {            // tanh-approx gelu (JAX default)
  float u = 0.7978845608028654f * (x + 0.044715f * x * x * x);
  float e = __expf(2.f * u);
  float th = 1.f - 2.f / (e + 1.f);
  return 0.5f * x * (1.f + th);
}

template <int BS>
DEV void blkreduce2(float& a, float& b) {
  __shared__ float ra[BS], rb[BS];
  int t = threadIdx.x;
  ra[t] = a; rb[t] = b; __syncthreads();
#pragma unroll
  for (int s = BS / 2; s > 0; s >>= 1) {
    if (t < s) { ra[t] += ra[t + s]; rb[t] += rb[t + s]; }
    __syncthreads();
  }
  a = ra[0]; b = rb[0];
  __syncthreads();
}

// ---------- dtype detector (validated round 3: inputs are fp32) ----------
__global__ void __launch_bounds__(256) detect_kernel(
    const unsigned short* __restrict__ xa, const unsigned short* __restrict__ wp,
    int* __restrict__ flg) {
  __shared__ int cnt[2];
  if (threadIdx.x < 2) cnt[threadIdx.x] = 0;
  __syncthreads();
  int l0 = 0, l1 = 0;
  for (int i = threadIdx.x; i < 1024; i += 256) {
    float v = bfu2f(xa[2 * i]); float a = fabsf(v);
    if (v == 0.f || (a > 1e-8f && a < 1e4f)) l0++;
    float u = bfu2f(wp[2 * i]); float bq = fabsf(u);
    if (u == 0.f || (bq > 1e-8f && bq < 1e4f)) l1++;
  }
  atomicAdd(&cnt[0], l0); atomicAdd(&cnt[1], l1);
  __syncthreads();
  if (threadIdx.x == 0) {
    flg[0] = (cnt[0] < 614) ? 1 : 0;
    flg[1] = (cnt[1] < 614) ? 1 : 0;
    flg[2] = 1;
  }
}

// ---------- zero-fill ----------
__global__ void __launch_bounds__(256) zero4_kernel(float4* __restrict__ p, int n4) {
  int i = blockIdx.x * 256 + threadIdx.x;
  if (i < n4) p[i] = make_float4(0.f, 0.f, 0.f, 0.f);
}

// ---------- depthwise 3x3x3 conv + residual (CPE), channels-last ----------
__global__ void __launch_bounds__(256) cpe_kernel(
    const void* __restrict__ xin, const void* __restrict__ w27,
    const void* __restrict__ bias, const int* __restrict__ flg, int afidx,
    float* __restrict__ out) {
  int af = flg[afidx], pf = flg[1];
  int idx = blockIdx.x * 256 + threadIdx.x;
  if (idx >= cBL * cC) return;
  int c = idx % cC; int bv = idx / cC;
  int v = bv & (cL - 1); int b = bv >> 13;
  int t = v >> 10, q = v & 1023, h = q >> 5, w = q & 31;
  float acc = ldsel(bias, c, pf);
#pragma unroll
  for (int dz = 0; dz < 3; ++dz) {
    int tt = t + dz - 1; if ((unsigned)tt >= (unsigned)cT) continue;
#pragma unroll
    for (int dy = 0; dy < 3; ++dy) {
      int hh = h + dy - 1; if ((unsigned)hh >= (unsigned)cH) continue;
#pragma unroll
      for (int dx = 0; dx < 3; ++dx) {
        int ww = w + dx - 1; if ((unsigned)ww >= (unsigned)cW) continue;
        int vv = (tt << 10) + (hh << 5) + ww;
        acc += ldsel(w27, c * 27 + dz * 9 + dy * 3 + dx, pf) *
               ldsel(xin, ((size_t)b * cL + vv) * cC + c, af);
      }
    }
  }
  out[idx] = ldsel(xin, idx, af) + acc;
}

// ---------- depthwise conv on DI channels + SiLU ----------
__global__ void __launch_bounds__(256) dwconv_silu_kernel(
    const float* __restrict__ xin, const void* __restrict__ w27,
    const void* __restrict__ bias, const int* __restrict__ flg,
    float* __restrict__ out) {
  int pf = flg[1];
  int idx = blockIdx.x * 256 + threadIdx.x;
  if (idx >= cBL * cDI) return;
  int d = idx % cDI; int bv = idx / cDI;
  int v = bv & (cL - 1); int b = bv >> 13;
  int t = v >> 10, q = v & 1023, h = q >> 5, w = q & 31;
  float acc = ldsel(bias, d, pf);
#pragma unroll
  for (int dz = 0; dz < 3; ++dz) {
    int tt = t + dz - 1; if ((unsigned)tt >= (unsigned)cT) continue;
#pragma unroll
    for (int dy = 0; dy < 3; ++dy) {
      int hh = h + dy - 1; if ((unsigned)hh >= (unsigned)cH) continue;
#pragma unroll
      for (int dx = 0; dx < 3; ++dx) {
        int ww = w + dx - 1; if ((unsigned)ww >= (unsigned)cW) continue;
        int vv = (tt << 10) + (hh << 5) + ww;
        acc += ldsel(w27, d * 27 + dz * 9 + dy * 3 + dx, pf) *
               xin[((size_t)b * cL + vv) * cDI + d];
      }
    }
  }
  out[idx] = siluf(acc);
}

// ---------- row LayerNorm ----------
__global__ void __launch_bounds__(256) ln_kernel(
    const float* __restrict__ in, const void* __restrict__ g,
    const void* __restrict__ bb, const int* __restrict__ flg,
    float* __restrict__ out, int D) {
  int pf = flg[1];
  int row = blockIdx.x;
  const float* x = in + (size_t)row * D;
  float s1 = 0.f, s2 = 0.f;
  for (int i = threadIdx.x; i < D; i += 256) { float v = x[i]; s1 += v; s2 += v * v; }
  blkreduce2<256>(s1, s2);
  float mean = s1 / D;
  float var = s2 / D - mean * mean;
  float rstd = rsqrtf(var + 1e-6f);
  float* o = out + (size_t)row * D;
  for (int i = threadIdx.x; i < D; i += 256)
    o[i] = (x[i] - mean) * rstd * ldsel(g, i, pf) + ldsel(bb, i, pf);
}

// ---------- text conditioning ----------
__global__ void __launch_bounds__(384) text_cond_kernel(
    const void* __restrict__ text, const void* __restrict__ tw,
    const void* __restrict__ tb, const int* __restrict__ flg,
    float* __restrict__ cond) {
  int af = flg[0], pf = flg[1];
  __shared__ float mean[cC];
  int b = blockIdx.x;
  for (int c = threadIdx.x; c < cC; c += 384) {
    float s = 0.f;
    for (int t = 0; t < cLT; ++t) s += ldsel(text, ((size_t)b * cLT + t) * cC + c, af);
    mean[c] = s * (1.f / cLT);
  }
  __syncthreads();
  int di = threadIdx.x;
  float a = ldsel(tb, di, pf);
  for (int c = 0; c < cC; ++c) a += mean[c] * ldsel(tw, di * cC + c, pf);
  cond[b * cDI + di] = siluf(a);
}

// ---------- MFMA GEMM: out = epilogue(A[M,K]fp32 @ W[N,K]^T), bf16 compute ----------
// Tile 128x64, 256 threads = 4 waves (2x2 of 64x32), BK=32, 16x16x32 bf16 MFMA.
// A/B frag: [row=lane&15][k=quad*8+j]; C/D: col=lane&15, row=quad*4+reg (m89-verified).
// MODE 0: in_proj -> xi(+bias+cond)/z(+bias); 1: x_proj scatter (stride XSTR);
// MODE 2: out_proj + x1; 3: fc1 gelu; 4: fc2 + bias + x3 -> d_out fp32
template <int MODE>
__global__ void __launch_bounds__(256) gemm_mfma_kernel(
    const float* __restrict__ A, const void* __restrict__ W,
    int N, int K, const void* __restrict__ bias, const int* __restrict__ flg,
    const float* __restrict__ extra, float* __restrict__ out,
    float* __restrict__ out2) {
  constexpr int BM = 128, BN = 64, BK = 32, PK = 40;  // PK: 2-way bank alias = free
  __shared__ short As[BM * PK];
  __shared__ short Bs[BN * PK];
  int pf = flg[1];
  int tid = threadIdx.x;
  int m0 = blockIdx.y * BM, n0 = blockIdx.x * BN;
  int lane = tid & 63, wv = tid >> 6;
  int wm = (wv >> 1) * 64, wn = (wv & 1) * 32;
  int lr = lane & 15, quad = lane >> 4;
  f32x4 acc[4][2];
#pragma unroll
  for (int mi = 0; mi < 4; ++mi)
#pragma unroll
    for (int ni = 0; ni < 2; ++ni) { acc[mi][ni][0]=0.f; acc[mi][ni][1]=0.f; acc[mi][ni][2]=0.f; acc[mi][ni][3]=0.f; }
  int ar = tid >> 1, aks = (tid & 1) * 16;   // A: 128 rows x 2 half-chunks
  int wr = tid >> 2, wks = (tid & 3) * 8;    // W: 64 rows x 4 chunks
  for (int k0 = 0; k0 < K; k0 += BK) {
    // stage A (fp32 ws -> bf16 LDS)
    {
      const float* ap = A + (size_t)(m0 + ar) * K + k0 + aks;
      short* da = &As[ar * PK + aks];
#pragma unroll
      for (int i = 0; i < 4; ++i) {
        float4 v = ((const float4*)ap)[i];
        short4v h; h.x = f2bf(v.x); h.y = f2bf(v.y); h.z = f2bf(v.z); h.w = f2bf(v.w);
        *(short4v*)(da + i * 4) = h;
      }
    }
    // stage W (flagged fp32/bf16 -> bf16 LDS)
    {
      int nr = n0 + wr;
      short hb[8];
      if (nr < N) {
        size_t wi = (size_t)nr * K + k0 + wks;
        if (pf) {
#pragma unroll
          for (int i = 0; i < 8; ++i) hb[i] = f2bf(((const float*)W)[wi + i]);
        } else {
#pragma unroll
          for (int i = 0; i < 8; ++i) hb[i] = (short)((const unsigned short*)W)[wi + i];
        }
      } else {
#pragma unroll
        for (int i = 0; i < 8; ++i) hb[i] = 0;
      }
      short* db = &Bs[wr * PK + wks];
#pragma unroll
      for (int i = 0; i < 8; i += 4) {
        short4v h; h.x = hb[i]; h.y = hb[i+1]; h.z = hb[i+2]; h.w = hb[i+3];
        *(short4v*)(db + i) = h;
      }
    }
    __syncthreads();
    bf16x8 af[4], bfr[2];
#pragma unroll
    for (int mi = 0; mi < 4; ++mi)
      af[mi] = *(const bf16x8*)&As[(wm + mi * 16 + lr) * PK + quad * 8];
#pragma unroll
    for (int ni = 0; ni < 2; ++ni)
      bfr[ni] = *(const bf16x8*)&Bs[(wn + ni * 16 + lr) * PK + quad * 8];
#pragma unroll
    for (int mi = 0; mi < 4; ++mi)
#pragma unroll
      for (int ni = 0; ni < 2; ++ni)
        acc[mi][ni] = __builtin_amdgcn_mfma_f32_16x16x32_bf16(af[mi], bfr[ni], acc[mi][ni], 0, 0, 0);
    __syncthreads();
  }
  // epilogue
#pragma unroll
  for (int mi = 0; mi < 4; ++mi) {
#pragma unroll
    for (int ni = 0; ni < 2; ++ni) {
#pragma unroll
      for (int r = 0; r < 4; ++r) {
        int m = m0 + wm + mi * 16 + quad * 4 + r;
        int n = n0 + wn + ni * 16 + lr;
        float v = acc[mi][ni][r];
        if (MODE == 0) {
          float bv = ldsel(bias, n, pf);
          int b = m >> 13;
          if (n < cDI) out[(size_t)m * cDI + n] = v + bv + extra[b * cDI + n];
          else         out2[(size_t)m * cDI + (n - cDI)] = v + bv;
        } else if (MODE == 1) {
          if (n < cK * XROW) {
            int k = n / XROW, c = n - k * XROW;
            int b = m >> 13, vv = m & (cL - 1);
            int t = vv >> 10, q = vv & 1023, h = q >> 5, w = q & 31;
            int l1 = (t << 10) + (w << 5) + h;
            int lk = (k == 0) ? vv : (k == 1) ? l1 : (k == 2) ? (cL - 1 - vv) : (cL - 1 - l1);
            out[((size_t)(b * cK + k) * cL + lk) * XSTR + c] = v;
          }
        } else if (MODE == 2) {
          out[(size_t)m * cC + n] = v + extra[(size_t)m * cC + n];
        } else if (MODE == 3) {
          out[(size_t)m * cHID + n] = gelut(v + ldsel(bias, n, pf));
        } else {
          out[(size_t)m * cC + n] = v + ldsel(bias, n, pf) + extra[(size_t)m * cC + n];
        }
      }
    }
  }
}

// voxel index for scan position l in direction k
DEV int scan_voxel(int k, int l) {
  if (k == 0) return l;
  if (k == 2) return cL - 1 - l;
  int ll = (k == 1) ? l : (cL - 1 - l);
  int t = ll >> 10, q = ll & 1023, w = q >> 5, h = q & 31;
  return (t << 10) + (h << 5) + w;
}

// Load padded xdbl row (wave-uniform) as float4s into registers
DEV void load_row(const float* __restrict__ rr, float* rv) {
#pragma unroll
  for (int i = 0; i < 11; ++i) *(float4*)&rv[i * 4] = ((const float4*)rr)[i];
}

// ---------- scan pass 1 ----------
__global__ void __launch_bounds__(128) scan1_kernel(
    const float* __restrict__ xc, const float* __restrict__ xdbl,
    const void* __restrict__ dtw, const void* __restrict__ dtbv,
    const void* __restrict__ alog, const void* __restrict__ dsv,
    const int* __restrict__ flg,
    float* __restrict__ ysm, float* __restrict__ hend, float* __restrict__ pend) {
  int pf = flg[1];
  int d = blockIdx.x * 128 + threadIdx.x;
  int bks = blockIdx.y;
  int s = bks & (SEG - 1); int bk = bks >> 6; int k = bk & 3; int b = bk >> 2;
  float wdt[cDTR];
#pragma unroll
  for (int r = 0; r < cDTR; ++r) wdt[r] = ldsel(dtw, (size_t)(k * cDI + d) * cDTR + r, pf);
  float dtb = ldsel(dtbv, k * cDI + d, pf);
  float ac[cN];
#pragma unroll
  for (int n = 0; n < cN; ++n)
    ac[n] = -__expf(ldsel(alog, (size_t)(k * cDI + d) * cN + n, pf)) * 1.4426950408889634f;
  // A_log = log(arange(1..N)) tiled -> ac[n] = (n+1)*ac[0]; verify at runtime
  bool fast = true;
#pragma unroll
  for (int n = 1; n < cN; ++n)
    fast = fast && (fabsf(ac[n] - (float)(n + 1) * ac[0]) <= 1e-3f * fabsf(ac[n]));
  float Dsd = ldsel(dsv, k * cDI + d, pf);
  float h[cN];
#pragma unroll
  for (int n = 0; n < cN; ++n) h[n] = 0.f;
  const float* xrow = xdbl + (size_t)bk * cL * XSTR;
  int l0 = s * SEGLEN;
  size_t so = ((size_t)bks * cDI + d) * cN;
  float rv[44];
  if (fast) {
    float P1 = 1.f;
    for (int st = 0; st < SEGLEN; ++st) {
      int l = l0 + st;
      load_row(xrow + (size_t)l * XSTR, rv);
      float draw = dtb;
#pragma unroll
      for (int r = 0; r < cDTR; ++r) draw += rv[r] * wdt[r];
      float dt = softplusf(draw);
      float a1 = exp2f(dt * ac[0]);       // exp(dt*A0); a[n] = a1^(n+1)
      int v = scan_voxel(k, l);
      float u = xc[((size_t)b * cL + v) * cDI + d];
      float dtu = dt * u;
      float y = Dsd * u;
      P1 *= a1;
      float ap = a1;
#pragma unroll
      for (int n = 0; n < cN; ++n) {
        h[n] = h[n] * ap + dtu * rv[cDTR + n];
        y += h[n] * rv[cDTR + cN + n];
        ap *= a1;
      }
      atomicAdd(&ysm[((size_t)b * cL + v) * cDI + d], y);
    }
    float pp = P1;
#pragma unroll
    for (int n = 0; n < cN; ++n) { hend[so + n] = h[n]; pend[so + n] = pp; pp *= P1; }
  } else {
    float P[cN];
#pragma unroll
    for (int n = 0; n < cN; ++n) P[n] = 1.f;
    for (int st = 0; st < SEGLEN; ++st) {
      int l = l0 + st;
      load_row(xrow + (size_t)l * XSTR, rv);
      float draw = dtb;
#pragma unroll
      for (int r = 0; r < cDTR; ++r) draw += rv[r] * wdt[r];
      float dt = softplusf(draw);
      int v = scan_voxel(k, l);
      float u = xc[((size_t)b * cL + v) * cDI + d];
      float dtu = dt * u;
      float y = Dsd * u;
#pragma unroll
      for (int n = 0; n < cN; ++n) {
        float a = exp2f(dt * ac[n]);
        h[n] = h[n] * a + dtu * rv[cDTR + n];
        P[n] *= a;
        y += h[n] * rv[cDTR + cN + n];
      }
      atomicAdd(&ysm[((size_t)b * cL + v) * cDI + d], y);
    }
#pragma unroll
    for (int n = 0; n < cN; ++n) { hend[so + n] = h[n]; pend[so + n] = P[n]; }
  }
}

// ---------- scan pass 2: inter-segment recurrence (hin in-place over hend) ----------
__global__ void __launch_bounds__(256) scan2_kernel(
    float* __restrict__ hend, const float* __restrict__ pend) {
  int tid = blockIdx.x * 256 + threadIdx.x;
  int bk = tid / (cDI * cN); int r = tid - bk * (cDI * cN);
  float g = 0.f;
  for (int s = 0; s < SEG; ++s) {
    size_t o = ((size_t)(bk * SEG + s) * cDI * cN) + r;
    float he = hend[o], pe = pend[o];
    hend[o] = g;
    g = pe * g + he;
  }
}

// ---------- scan pass 3 ----------
__global__ void __launch_bounds__(128) scan3_kernel(
    const float* __restrict__ xdbl,
    const void* __restrict__ dtw, const void* __restrict__ dtbv,
    const void* __restrict__ alog, const int* __restrict__ flg,
    const float* __restrict__ hin, float* __restrict__ ysm) {
  int bks = blockIdx.y;
  int s = bks & (SEG - 1);
  if (s == 0) return;
  int pf = flg[1];
  int d = blockIdx.x * 128 + threadIdx.x;
  int bk = bks >> 6; int k = bk & 3; int b = bk >> 2;
  float wdt[cDTR];
#pragma unroll
  for (int r = 0; r < cDTR; ++r) wdt[r] = ldsel(dtw, (size_t)(k * cDI + d) * cDTR + r, pf);
  float dtb = ldsel(dtbv, k * cDI + d, pf);
  float ac[cN];
#pragma unroll
  for (int n = 0; n < cN; ++n)
    ac[n] = -__expf(ldsel(alog, (size_t)(k * cDI + d) * cN + n, pf)) * 1.4426950408889634f;
  bool fast = true;
#pragma unroll
  for (int n = 1; n < cN; ++n)
    fast = fast && (fabsf(ac[n] - (float)(n + 1) * ac[0]) <= 1e-3f * fabsf(ac[n]));
  float g[cN];
  size_t so = ((size_t)bks * cDI + d) * cN;
#pragma unroll
  for (int n = 0; n < cN; ++n) g[n] = hin[so + n];
  const float* xrow = xdbl + (size_t)bk * cL * XSTR;
  int l0 = s * SEGLEN;
  float rv[44];
  if (fast) {
    for (int st = 0; st < SEGLEN; ++st) {
      int l = l0 + st;
      load_row(xrow + (size_t)l * XSTR, rv);
      float draw = dtb;
#pragma unroll
      for (int r = 0; r < cDTR; ++r) draw += rv[r] * wdt[r];
      float dt = softplusf(draw);
      float a1 = exp2f(dt * ac[0]);
      float ap = a1;
      float y = 0.f;
#pragma unroll
      for (int n = 0; n < cN; ++n) {
        g[n] *= ap;
        y += g[n] * rv[cDTR + cN + n];
        ap *= a1;
      }
      int v = scan_voxel(k, l);
      atomicAdd(&ysm[((size_t)b * cL + v) * cDI + d], y);
    }
  } else {
    for (int st = 0; st < SEGLEN; ++st) {
      int l = l0 + st;
      load_row(xrow + (size_t)l * XSTR, rv);
      float draw = dtb;
#pragma unroll
      for (int r = 0; r < cDTR; ++r) draw += rv[r] * wdt[r];
      float dt = softplusf(draw);
      float y = 0.f;
#pragma unroll
      for (int n = 0; n < cN; ++n) {
        float a = exp2f(dt * ac[n]);
        g[n] *= a;
        y += g[n] * rv[cDTR + cN + n];
      }
      int v = scan_voxel(k, l);
      atomicAdd(&ysm[((size_t)b * cL + v) * cDI + d], y);
    }
  }
}

// ---------- out_norm LN over merged ysm + silu(z) gate ----------
__global__ void __launch_bounds__(128) merge_kernel(
    const float* __restrict__ ysm, const float* __restrict__ z,
    const void* __restrict__ ong, const void* __restrict__ onb,
    const int* __restrict__ flg, float* __restrict__ yg) {
  int pf = flg[1];
  int bv = blockIdx.x;
  const float* yr = ysm + (size_t)bv * cDI;
  float vals[3]; float s1 = 0.f, s2 = 0.f;
#pragma unroll
  for (int i = 0; i < 3; ++i) {
    int d = threadIdx.x + i * 128;
    float x = yr[d];
    vals[i] = x; s1 += x; s2 += x * x;
  }
  blkreduce2<128>(s1, s2);
  float mean = s1 * (1.f / cDI);
  float var = s2 * (1.f / cDI) - mean * mean;
  float rstd = rsqrtf(var + 1e-6f);
  const float* zr = z + (size_t)bv * cDI;
  float* og = yg + (size_t)bv * cDI;
#pragma unroll
  for (int i = 0; i < 3; ++i) {
    int d = threadIdx.x + i * 128;
    float xn = (vals[i] - mean) * rstd * ldsel(ong, d, pf) + ldsel(onb, d, pf);
    og[d] = xn * siluf(zr[d]);
  }
}

}  // namespace

extern "C" void kernel_launch(void* const* d_in, const int* in_sizes, int n_in,
                              void* d_out, int out_size, void* d_ws, size_t ws_size,
                              hipStream_t stream) {
  (void)in_sizes; (void)n_in; (void)out_size; (void)ws_size;
  const void* x    = d_in[0];
  const void* text = d_in[1];
  const void* c1w  = d_in[2];
  const void* c1b  = d_in[3];
  const void* c2w  = d_in[4];
  const void* c2b  = d_in[5];
  const void* n1g  = d_in[6];
  const void* n1b  = d_in[7];
  const void* n2g  = d_in[8];
  const void* n2b  = d_in[9];
  const void* ipw  = d_in[10];
  const void* ipb  = d_in[11];
  const void* tpw  = d_in[12];
  const void* tpb  = d_in[13];
  const void* cvw  = d_in[14];
  const void* cvb  = d_in[15];
  const void* xpw  = d_in[16];
  const void* dtw  = d_in[17];
  const void* dtb  = d_in[18];
  const void* alog = d_in[19];
  const void* dsv  = d_in[20];
  const void* ong  = d_in[21];
  const void* onb  = d_in[22];
  const void* opw  = d_in[23];
  const void* f1w  = d_in[24];
  const void* f1b  = d_in[25];
  const void* f2w  = d_in[26];
  const void* f2b  = d_in[27];

  float* Wf = (float*)d_ws;

  // ---- slot arena (~125.8 MB). xdbl padded to XSTR=48 this round. ----
  // liveness: C: xc(5-8)/hbuf(15-16); D: xdbl(7-10)/hbuf; G: xn(2-4),pend(8-9)/hbuf;
  //           A: xi(4-5),ysm(6-11),x2(12-13); B: z/yg(4-12),x3(13-16);
  //           E: x1(1-12); F: hend-hin(8-10),xn2(14-15).  hbuf = C+D+G exactly.
  constexpr size_t oC  = 0;                              // 6,291,456
  constexpr size_t oD  = 6291456;                        // 3,145,728 (BK*... 2*4*8192*48)
  constexpr size_t oG  = 9437184;                        // 3,145,728
  constexpr size_t oA  = 12582912;                       // 6,291,456
  constexpr size_t oB  = 18874368;                       // 6,291,456
  constexpr size_t oE  = 25165824;                       // 3,145,728
  constexpr size_t oF  = 28311552;                       // 3,145,728
  constexpr size_t oCO = 31457280;                       // 768 (cond)
  constexpr size_t oFL = 31458048;                       // 4 ints (flags)
  float* xc   = Wf + oC;
  float* xdbl = Wf + oD;
  float* xn   = Wf + oG;
  float* pend = Wf + oG;
  float* xi   = Wf + oA;
  float* ysm  = Wf + oA;
  float* x2   = Wf + oA;
  float* z    = Wf + oB;
  float* yg   = Wf + oB;
  float* x3   = Wf + oB;
  float* x1   = Wf + oE;
  float* hend = Wf + oF;
  float* xn2  = Wf + oF;
  float* cond = Wf + oCO;
  float* hbuf = Wf + oC;   // 12,582,912 floats = slots C+D+G exactly
  int*   flg  = (int*)(Wf + oFL);

  const int eltBlocksC  = (cBL * cC + 255) / 256;
  const int eltBlocksDI = (cBL * cDI + 255) / 256;

  // 0. dtype detection
  hipLaunchKernelGGL(detect_kernel, dim3(1), dim3(256), 0, stream,
                     (const unsigned short*)x, (const unsigned short*)ipw, flg);
  // 1. x1 = x + cpe1(x)
  hipLaunchKernelGGL(cpe_kernel, dim3(eltBlocksC), dim3(256), 0, stream,
                     x, c1w, c1b, flg, 0, x1);
  // 2. xn = LN1(x1)
  hipLaunchKernelGGL(ln_kernel, dim3(cBL), dim3(256), 0, stream, x1, n1g, n1b, flg, xn, cC);
  // 3. cond
  hipLaunchKernelGGL(text_cond_kernel, dim3(cB), dim3(384), 0, stream, text, tpw, tpb, flg, cond);
  // 4. in_proj (MFMA): xn -> xi (+cond), z
  hipLaunchKernelGGL((gemm_mfma_kernel<0>), dim3(2 * cDI / 64, cBL / 128), dim3(256), 0, stream,
                     xn, ipw, 2 * cDI, cC, ipb, flg, cond, xi, z);
  // 5. xc = silu(dwconv(xi))
  hipLaunchKernelGGL(dwconv_silu_kernel, dim3(eltBlocksDI), dim3(256), 0, stream,
                     xi, cvw, cvb, flg, xc);
  // 6. zero ysm
  hipLaunchKernelGGL(zero4_kernel, dim3(cBL * cDI / 4 / 256), dim3(256), 0, stream,
                     (float4*)ysm, cBL * cDI / 4);
  // 7. x_proj (MFMA, scatter to padded scan rows)
  hipLaunchKernelGGL((gemm_mfma_kernel<1>), dim3((cK * XROW + 63) / 64, cBL / 128), dim3(256), 0, stream,
                     xc, xpw, cK * XROW, cDI, (const void*)nullptr, flg,
                     (const float*)nullptr, xdbl, (float*)nullptr);
  // 8-10. chunked selective scan
  hipLaunchKernelGGL(scan1_kernel, dim3(cDI / 128, cB * cK * SEG), dim3(128), 0, stream,
                     xc, xdbl, dtw, dtb, alog, dsv, flg, ysm, hend, pend);
  hipLaunchKernelGGL(scan2_kernel, dim3(cB * cK * cDI * cN / 256), dim3(256), 0, stream,
                     hend, pend);
  hipLaunchKernelGGL(scan3_kernel, dim3(cDI / 128, cB * cK * SEG), dim3(128), 0, stream,
                     xdbl, dtw, dtb, alog, flg, hend, ysm);
  // 11. out_norm + gate
  hipLaunchKernelGGL(merge_kernel, dim3(cBL), dim3(128), 0, stream, ysm, z, ong, onb, flg, yg);
  // 12. out_proj + residual(x1) -> x2 (MFMA)
  hipLaunchKernelGGL((gemm_mfma_kernel<2>), dim3(cC / 64, cBL / 128), dim3(256), 0, stream,
                     yg, opw, cC, cDI, (const void*)nullptr, flg, x1, x2,
                     (float*)nullptr);
  // 13. x3 = x2 + cpe2(x2)
  hipLaunchKernelGGL(cpe_kernel, dim3(eltBlocksC), dim3(256), 0, stream,
                     x2, c2w, c2b, flg, 2, x3);
  // 14. xn2 = LN2(x3)
  hipLaunchKernelGGL(ln_kernel, dim3(cBL), dim3(256), 0, stream, x3, n2g, n2b, flg, xn2, cC);
  // 15. fc1 + gelu -> hbuf (MFMA)
  hipLaunchKernelGGL((gemm_mfma_kernel<3>), dim3(cHID / 64, cBL / 128), dim3(256), 0, stream,
                     xn2, f1w, cHID, cC, f1b, flg, (const float*)nullptr, hbuf,
                     (float*)nullptr);
  // 16. fc2 + bias + residual(x3) -> d_out fp32 (MFMA)
  hipLaunchKernelGGL((gemm_mfma_kernel<4>), dim3(cC / 64, cBL / 128), dim3(256), 0, stream,
                     hbuf, f2w, cC, cHID, f2b, flg, x3, (float*)d_out,
                     (float*)nullptr);
}

// Round 6
// 696.255 us; speedup vs baseline: 2.1925x; 1.4862x over previous
//
#include <hip/hip_runtime.h>
#include <hip/hip_bf16.h>

#define DEV __device__ __forceinline__

namespace {

constexpr int cB = 2, cT = 8, cH = 32, cW = 32, cC = 192;
constexpr int cDI = 384, cN = 16, cK = 4, cDTR = 12, cLT = 77, cHID = 768;
constexpr int cL  = cT * cH * cW;      // 8192
constexpr int cBL = cB * cL;           // 16384
constexpr int SEG = 64, SEGLEN = cL / SEG;   // 64 segments x 128 steps
constexpr int XROW = cDTR + 2 * cN;    // 44 live cols
constexpr int XSTR = 48;               // padded row stride (float4-aligned)

typedef __attribute__((ext_vector_type(8))) short bf16x8;
typedef __attribute__((ext_vector_type(4))) float f32x4;
typedef __attribute__((ext_vector_type(4))) short short4v;

// ---------- scalar helpers ----------
DEV float bfu2f(unsigned short u) { return __uint_as_float(((unsigned)u) << 16); }
DEV float ldsel(const void* p, size_t i, int f32) {
  return f32 ? ((const float*)p)[i] : bfu2f(((const unsigned short*)p)[i]);
}
template <int F32>
DEV float4 ld4(const void* p, size_t e) {   // e: element index, multiple of 4
  if (F32) return *(const float4*)((const float*)p + e);
  ushort4 u = *(const ushort4*)((const unsigned short*)p + e);
  return make_float4(bfu2f(u.x), bfu2f(u.y), bfu2f(u.z), bfu2f(u.w));
}
DEV short f2bf(float f) {   // RNE float->bf16 bits
  unsigned u = __float_as_uint(f);
  u += 0x7fffu + ((u >> 16) & 1u);
  return (short)(u >> 16);
}
DEV float siluf(float x) { return x / (1.f + __expf(-x)); }
DEV float softplusf(float x) { return (x > 20.f) ? x : __logf(1.f + __expf(x)); }
DEV float gelut(float x) {            // tanh-approx gelu (JAX default)
  float u = 0.7978845608028654f * (x + 0.044715f * x * x * x);
  float e = __expf(2.f * u);
  float th = 1.f - 2.f / (e + 1.f);
  return 0.5f * x * (1.f + th);
}

template <int BS>
DEV void blkreduce2(float& a, float& b) {
  __shared__ float ra[BS], rb[BS];
  int t = threadIdx.x;
  ra[t] = a; rb[t] = b; __syncthreads();
#pragma unroll
  for (int s = BS / 2; s > 0; s >>= 1) {
    if (t < s) { ra[t] += ra[t + s]; rb[t] += rb[t + s]; }
    __syncthreads();
  }
  a = ra[0]; b = rb[0];
  __syncthreads();
}

// ---------- dtype detector (validated round 3: inputs are fp32) ----------
__global__ void __launch_bounds__(256) detect_kernel(
    const unsigned short* __restrict__ xa, const unsigned short* __restrict__ wp,
    int* __restrict__ flg) {
  __shared__ int cnt[2];
  if (threadIdx.x < 2) cnt[threadIdx.x] = 0;
  __syncthreads();
  int l0 = 0, l1 = 0;
  for (int i = threadIdx.x; i < 1024; i += 256) {
    float v = bfu2f(xa[2 * i]); float a = fabsf(v);
    if (v == 0.f || (a > 1e-8f && a < 1e4f)) l0++;
    float u = bfu2f(wp[2 * i]); float bq = fabsf(u);
    if (u == 0.f || (bq > 1e-8f && bq < 1e4f)) l1++;
  }
  atomicAdd(&cnt[0], l0); atomicAdd(&cnt[1], l1);
  __syncthreads();
  if (threadIdx.x == 0) {
    flg[0] = (cnt[0] < 614) ? 1 : 0;
    flg[1] = (cnt[1] < 614) ? 1 : 0;
    flg[2] = 1;
  }
}

// ---------- zero-fill ----------
__global__ void __launch_bounds__(256) zero4_kernel(float4* __restrict__ p, int n4) {
  int i = blockIdx.x * 256 + threadIdx.x;
  if (i < n4) p[i] = make_float4(0.f, 0.f, 0.f, 0.f);
}

// ---------- conv weight prep: transpose [Ch][27] -> [27][Ch] fp32, decode biases ----------
__global__ void __launch_bounds__(256) prep_kernel(
    const void* __restrict__ cvw, const void* __restrict__ cvb,
    const void* __restrict__ c1w, const void* __restrict__ c1b,
    const void* __restrict__ c2w, const void* __restrict__ c2b,
    const int* __restrict__ flg,
    float* __restrict__ wcv, float* __restrict__ bcv,
    float* __restrict__ w1, float* __restrict__ b1,
    float* __restrict__ w2, float* __restrict__ b2) {
  int pf = flg[1];
  int i = blockIdx.x * 256 + threadIdx.x;
  int r = i;
  if (r < 27 * cDI) { int j = r / cDI, d = r % cDI; wcv[r] = ldsel(cvw, (size_t)d * 27 + j, pf); return; }
  r -= 27 * cDI;
  if (r < cDI) { bcv[r] = ldsel(cvb, r, pf); return; }
  r -= cDI;
  if (r < 27 * cC) { int j = r / cC, c = r % cC; w1[r] = ldsel(c1w, (size_t)c * 27 + j, pf); return; }
  r -= 27 * cC;
  if (r < cC) { b1[r] = ldsel(c1b, r, pf); return; }
  r -= cC;
  if (r < 27 * cC) { int j = r / cC, c = r % cC; w2[r] = ldsel(c2w, (size_t)c * 27 + j, pf); return; }
  r -= 27 * cC;
  if (r < cC) { b2[r] = ldsel(c2b, r, pf); return; }
}

// ---------- CPE (depthwise 3x3x3 + residual), 4-channel vectorized ----------
template <int F32>
DEV void cpe_body(const void* __restrict__ xin, const float* __restrict__ wT,
                  const float* __restrict__ bs, int idx, float* __restrict__ out) {
  int c = (idx % (cC / 4)) * 4; int bv = idx / (cC / 4);
  int v = bv & (cL - 1); int b = bv >> 13;
  int t = v >> 10, q = v & 1023, h = q >> 5, w = q & 31;
  float4 acc = *(const float4*)(bs + c);
#pragma unroll
  for (int dz = 0; dz < 3; ++dz) {
    int tt = t + dz - 1; if ((unsigned)tt >= (unsigned)cT) continue;
#pragma unroll
    for (int dy = 0; dy < 3; ++dy) {
      int hh = h + dy - 1; if ((unsigned)hh >= (unsigned)cH) continue;
#pragma unroll
      for (int dx = 0; dx < 3; ++dx) {
        int ww = w + dx - 1; if ((unsigned)ww >= (unsigned)cW) continue;
        int vv = (tt << 10) + (hh << 5) + ww;
        float4 wv = *(const float4*)(wT + (dz * 9 + dy * 3 + dx) * cC + c);
        float4 xv = ld4<F32>(xin, ((size_t)b * cL + vv) * cC + c);
        acc.x += wv.x * xv.x; acc.y += wv.y * xv.y;
        acc.z += wv.z * xv.z; acc.w += wv.w * xv.w;
      }
    }
  }
  float4 x0 = ld4<F32>(xin, (size_t)bv * cC + c);
  float4 o = make_float4(x0.x + acc.x, x0.y + acc.y, x0.z + acc.z, x0.w + acc.w);
  *(float4*)(out + (size_t)bv * cC + c) = o;
}

__global__ void __launch_bounds__(256) cpe_kernel(
    const void* __restrict__ xin, const float* __restrict__ wT,
    const float* __restrict__ bs, const int* __restrict__ flg, int afidx,
    float* __restrict__ out) {
  int idx = blockIdx.x * 256 + threadIdx.x;
  if (idx >= cBL * cC / 4) return;
  if (flg[afidx]) cpe_body<1>(xin, wT, bs, idx, out);
  else            cpe_body<0>(xin, wT, bs, idx, out);
}

// ---------- depthwise conv on DI + SiLU, 4-channel vectorized ----------
__global__ void __launch_bounds__(256) dwconv_silu_kernel(
    const float* __restrict__ xin, const float* __restrict__ wT,
    const float* __restrict__ bs, float* __restrict__ out) {
  int idx = blockIdx.x * 256 + threadIdx.x;
  if (idx >= cBL * cDI / 4) return;
  int d = (idx % (cDI / 4)) * 4; int bv = idx / (cDI / 4);
  int v = bv & (cL - 1); int b = bv >> 13;
  int t = v >> 10, q = v & 1023, h = q >> 5, w = q & 31;
  float4 acc = *(const float4*)(bs + d);
#pragma unroll
  for (int dz = 0; dz < 3; ++dz) {
    int tt = t + dz - 1; if ((unsigned)tt >= (unsigned)cT) continue;
#pragma unroll
    for (int dy = 0; dy < 3; ++dy) {
      int hh = h + dy - 1; if ((unsigned)hh >= (unsigned)cH) continue;
#pragma unroll
      for (int dx = 0; dx < 3; ++dx) {
        int ww = w + dx - 1; if ((unsigned)ww >= (unsigned)cW) continue;
        int vv = (tt << 10) + (hh << 5) + ww;
        float4 wv = *(const float4*)(wT + (dz * 9 + dy * 3 + dx) * cDI + d);
        float4 xv = *(const float4*)(xin + ((size_t)b * cL + vv) * cDI + d);
        acc.x += wv.x * xv.x; acc.y += wv.y * xv.y;
        acc.z += wv.z * xv.z; acc.w += wv.w * xv.w;
      }
    }
  }
  float4 o = make_float4(siluf(acc.x), siluf(acc.y), siluf(acc.z), siluf(acc.w));
  *(float4*)(out + (size_t)bv * cDI + d) = o;
}

// ---------- row LayerNorm ----------
__global__ void __launch_bounds__(256) ln_kernel(
    const float* __restrict__ in, const void* __restrict__ g,
    const void* __restrict__ bb, const int* __restrict__ flg,
    float* __restrict__ out, int D) {
  int pf = flg[1];
  int row = blockIdx.x;
  const float* x = in + (size_t)row * D;
  float s1 = 0.f, s2 = 0.f;
  for (int i = threadIdx.x; i < D; i += 256) { float v = x[i]; s1 += v; s2 += v * v; }
  blkreduce2<256>(s1, s2);
  float mean = s1 / D;
  float var = s2 / D - mean * mean;
  float rstd = rsqrtf(var + 1e-6f);
  float* o = out + (size_t)row * D;
  for (int i = threadIdx.x; i < D; i += 256)
    o[i] = (x[i] - mean) * rstd * ldsel(g, i, pf) + ldsel(bb, i, pf);
}

// ---------- text conditioning ----------
__global__ void __launch_bounds__(384) text_cond_kernel(
    const void* __restrict__ text, const void* __restrict__ tw,
    const void* __restrict__ tb, const int* __restrict__ flg,
    float* __restrict__ cond) {
  int af = flg[0], pf = flg[1];
  __shared__ float mean[cC];
  int b = blockIdx.x;
  for (int c = threadIdx.x; c < cC; c += 384) {
    float s = 0.f;
    for (int t = 0; t < cLT; ++t) s += ldsel(text, ((size_t)b * cLT + t) * cC + c, af);
    mean[c] = s * (1.f / cLT);
  }
  __syncthreads();
  int di = threadIdx.x;
  float a = ldsel(tb, di, pf);
  for (int c = 0; c < cC; ++c) a += mean[c] * ldsel(tw, di * cC + c, pf);
  cond[b * cDI + di] = siluf(a);
}

// ---------- MFMA GEMM: out = epilogue(A[M,K]fp32 @ W[N,K]^T), bf16 compute ----------
// Tile 128x64, 256 threads = 4 waves (2x2 of 64x32), BK=32, 16x16x32 bf16 MFMA.
template <int MODE>
__global__ void __launch_bounds__(256) gemm_mfma_kernel(
    const float* __restrict__ A, const void* __restrict__ W,
    int N, int K, const void* __restrict__ bias, const int* __restrict__ flg,
    const float* __restrict__ extra, float* __restrict__ out,
    float* __restrict__ out2) {
  constexpr int BM = 128, BN = 64, BK = 32, PK = 40;
  __shared__ short As[BM * PK];
  __shared__ short Bs[BN * PK];
  int pf = flg[1];
  int tid = threadIdx.x;
  int m0 = blockIdx.y * BM, n0 = blockIdx.x * BN;
  int lane = tid & 63, wv = tid >> 6;
  int wm = (wv >> 1) * 64, wn = (wv & 1) * 32;
  int lr = lane & 15, quad = lane >> 4;
  f32x4 acc[4][2];
#pragma unroll
  for (int mi = 0; mi < 4; ++mi)
#pragma unroll
    for (int ni = 0; ni < 2; ++ni) { acc[mi][ni][0]=0.f; acc[mi][ni][1]=0.f; acc[mi][ni][2]=0.f; acc[mi][ni][3]=0.f; }
  int ar = tid >> 1, aks = (tid & 1) * 16;
  int wr = tid >> 2, wks = (tid & 3) * 8;
  for (int k0 = 0; k0 < K; k0 += BK) {
    {
      const float* ap = A + (size_t)(m0 + ar) * K + k0 + aks;
      short* da = &As[ar * PK + aks];
#pragma unroll
      for (int i = 0; i < 4; ++i) {
        float4 v = ((const float4*)ap)[i];
        short4v h; h.x = f2bf(v.x); h.y = f2bf(v.y); h.z = f2bf(v.z); h.w = f2bf(v.w);
        *(short4v*)(da + i * 4) = h;
      }
    }
    {
      int nr = n0 + wr;
      short hb[8];
      if (nr < N) {
        size_t wi = (size_t)nr * K + k0 + wks;
        if (pf) {
#pragma unroll
          for (int i = 0; i < 8; ++i) hb[i] = f2bf(((const float*)W)[wi + i]);
        } else {
#pragma unroll
          for (int i = 0; i < 8; ++i) hb[i] = (short)((const unsigned short*)W)[wi + i];
        }
      } else {
#pragma unroll
        for (int i = 0; i < 8; ++i) hb[i] = 0;
      }
      short* db = &Bs[wr * PK + wks];
#pragma unroll
      for (int i = 0; i < 8; i += 4) {
        short4v h; h.x = hb[i]; h.y = hb[i+1]; h.z = hb[i+2]; h.w = hb[i+3];
        *(short4v*)(db + i) = h;
      }
    }
    __syncthreads();
    bf16x8 af[4], bfr[2];
#pragma unroll
    for (int mi = 0; mi < 4; ++mi)
      af[mi] = *(const bf16x8*)&As[(wm + mi * 16 + lr) * PK + quad * 8];
#pragma unroll
    for (int ni = 0; ni < 2; ++ni)
      bfr[ni] = *(const bf16x8*)&Bs[(wn + ni * 16 + lr) * PK + quad * 8];
#pragma unroll
    for (int mi = 0; mi < 4; ++mi)
#pragma unroll
      for (int ni = 0; ni < 2; ++ni)
        acc[mi][ni] = __builtin_amdgcn_mfma_f32_16x16x32_bf16(af[mi], bfr[ni], acc[mi][ni], 0, 0, 0);
    __syncthreads();
  }
#pragma unroll
  for (int mi = 0; mi < 4; ++mi) {
#pragma unroll
    for (int ni = 0; ni < 2; ++ni) {
#pragma unroll
      for (int r = 0; r < 4; ++r) {
        int m = m0 + wm + mi * 16 + quad * 4 + r;
        int n = n0 + wn + ni * 16 + lr;
        float v = acc[mi][ni][r];
        if (MODE == 0) {
          float bv = ldsel(bias, n, pf);
          int b = m >> 13;
          if (n < cDI) out[(size_t)m * cDI + n] = v + bv + extra[b * cDI + n];
          else         out2[(size_t)m * cDI + (n - cDI)] = v + bv;
        } else if (MODE == 1) {
          if (n < cK * XROW) {
            int k = n / XROW, c = n - k * XROW;
            int b = m >> 13, vv = m & (cL - 1);
            int t = vv >> 10, q = vv & 1023, h = q >> 5, w = q & 31;
            int l1 = (t << 10) + (w << 5) + h;
            int lk = (k == 0) ? vv : (k == 1) ? l1 : (k == 2) ? (cL - 1 - vv) : (cL - 1 - l1);
            out[((size_t)(b * cK + k) * cL + lk) * XSTR + c] = v;
          }
        } else if (MODE == 2) {
          out[(size_t)m * cC + n] = v + extra[(size_t)m * cC + n];
        } else if (MODE == 3) {
          out[(size_t)m * cHID + n] = gelut(v + ldsel(bias, n, pf));
        } else {
          out[(size_t)m * cC + n] = v + ldsel(bias, n, pf) + extra[(size_t)m * cC + n];
        }
      }
    }
  }
}

// voxel index for scan position l in direction k
DEV int scan_voxel(int k, int l) {
  if (k == 0) return l;
  if (k == 2) return cL - 1 - l;
  int ll = (k == 1) ? l : (cL - 1 - l);
  int t = ll >> 10, q = ll & 1023, w = q >> 5, h = q & 31;
  return (t << 10) + (h << 5) + w;
}

DEV void load_row(const float* __restrict__ rr, float* rv) {
#pragma unroll
  for (int i = 0; i < 11; ++i) *(float4*)&rv[i * 4] = ((const float4*)rr)[i];
}

// ---------- scan pass 1 ----------
__global__ void __launch_bounds__(128) scan1_kernel(
    const float* __restrict__ xc, const float* __restrict__ xdbl,
    const void* __restrict__ dtw, const void* __restrict__ dtbv,
    const void* __restrict__ alog, const void* __restrict__ dsv,
    const int* __restrict__ flg,
    float* __restrict__ ysm, float* __restrict__ hend, float* __restrict__ pend) {
  int pf = flg[1];
  int d = blockIdx.x * 128 + threadIdx.x;
  int bks = blockIdx.y;
  int s = bks & (SEG - 1); int bk = bks >> 6; int k = bk & 3; int b = bk >> 2;
  float wdt[cDTR];
#pragma unroll
  for (int r = 0; r < cDTR; ++r) wdt[r] = ldsel(dtw, (size_t)(k * cDI + d) * cDTR + r, pf);
  float dtb = ldsel(dtbv, k * cDI + d, pf);
  float ac[cN];
#pragma unroll
  for (int n = 0; n < cN; ++n)
    ac[n] = -__expf(ldsel(alog, (size_t)(k * cDI + d) * cN + n, pf)) * 1.4426950408889634f;
  bool fast = true;
#pragma unroll
  for (int n = 1; n < cN; ++n)
    fast = fast && (fabsf(ac[n] - (float)(n + 1) * ac[0]) <= 1e-3f * fabsf(ac[n]));
  float Dsd = ldsel(dsv, k * cDI + d, pf);
  float h[cN];
#pragma unroll
  for (int n = 0; n < cN; ++n) h[n] = 0.f;
  const float* xrow = xdbl + (size_t)bk * cL * XSTR;
  int l0 = s * SEGLEN;
  size_t so = ((size_t)bks * cDI + d) * cN;
  float rv[44];
  if (fast) {
    float P1 = 1.f;
    for (int st = 0; st < SEGLEN; ++st) {
      int l = l0 + st;
      load_row(xrow + (size_t)l * XSTR, rv);
      float draw = dtb;
#pragma unroll
      for (int r = 0; r < cDTR; ++r) draw += rv[r] * wdt[r];
      float dt = softplusf(draw);
      float a1 = exp2f(dt * ac[0]);
      int v = scan_voxel(k, l);
      float u = xc[((size_t)b * cL + v) * cDI + d];
      float dtu = dt * u;
      float y = Dsd * u;
      P1 *= a1;
      float ap = a1;
#pragma unroll
      for (int n = 0; n < cN; ++n) {
        h[n] = h[n] * ap + dtu * rv[cDTR + n];
        y += h[n] * rv[cDTR + cN + n];
        ap *= a1;
      }
      atomicAdd(&ysm[((size_t)b * cL + v) * cDI + d], y);
    }
    float pp = P1;
#pragma unroll
    for (int n = 0; n < cN; ++n) { hend[so + n] = h[n]; pend[so + n] = pp; pp *= P1; }
  } else {
    float P[cN];
#pragma unroll
    for (int n = 0; n < cN; ++n) P[n] = 1.f;
    for (int st = 0; st < SEGLEN; ++st) {
      int l = l0 + st;
      load_row(xrow + (size_t)l * XSTR, rv);
      float draw = dtb;
#pragma unroll
      for (int r = 0; r < cDTR; ++r) draw += rv[r] * wdt[r];
      float dt = softplusf(draw);
      int v = scan_voxel(k, l);
      float u = xc[((size_t)b * cL + v) * cDI + d];
      float dtu = dt * u;
      float y = Dsd * u;
#pragma unroll
      for (int n = 0; n < cN; ++n) {
        float a = exp2f(dt * ac[n]);
        h[n] = h[n] * a + dtu * rv[cDTR + n];
        P[n] *= a;
        y += h[n] * rv[cDTR + cN + n];
      }
      atomicAdd(&ysm[((size_t)b * cL + v) * cDI + d], y);
    }
#pragma unroll
    for (int n = 0; n < cN; ++n) { hend[so + n] = h[n]; pend[so + n] = P[n]; }
  }
}

// ---------- scan pass 2 ----------
__global__ void __launch_bounds__(256) scan2_kernel(
    float* __restrict__ hend, const float* __restrict__ pend) {
  int tid = blockIdx.x * 256 + threadIdx.x;
  int bk = tid / (cDI * cN); int r = tid - bk * (cDI * cN);
  float g = 0.f;
  for (int s = 0; s < SEG; ++s) {
    size_t o = ((size_t)(bk * SEG + s) * cDI * cN) + r;
    float he = hend[o], pe = pend[o];
    hend[o] = g;
    g = pe * g + he;
  }
}

// ---------- scan pass 3 ----------
__global__ void __launch_bounds__(128) scan3_kernel(
    const float* __restrict__ xdbl,
    const void* __restrict__ dtw, const void* __restrict__ dtbv,
    const void* __restrict__ alog, const int* __restrict__ flg,
    const float* __restrict__ hin, float* __restrict__ ysm) {
  int bks = blockIdx.y;
  int s = bks & (SEG - 1);
  if (s == 0) return;
  int pf = flg[1];
  int d = blockIdx.x * 128 + threadIdx.x;
  int bk = bks >> 6; int k = bk & 3; int b = bk >> 2;
  float wdt[cDTR];
#pragma unroll
  for (int r = 0; r < cDTR; ++r) wdt[r] = ldsel(dtw, (size_t)(k * cDI + d) * cDTR + r, pf);
  float dtb = ldsel(dtbv, k * cDI + d, pf);
  float ac[cN];
#pragma unroll
  for (int n = 0; n < cN; ++n)
    ac[n] = -__expf(ldsel(alog, (size_t)(k * cDI + d) * cN + n, pf)) * 1.4426950408889634f;
  bool fast = true;
#pragma unroll
  for (int n = 1; n < cN; ++n)
    fast = fast && (fabsf(ac[n] - (float)(n + 1) * ac[0]) <= 1e-3f * fabsf(ac[n]));
  float g[cN];
  size_t so = ((size_t)bks * cDI + d) * cN;
#pragma unroll
  for (int n = 0; n < cN; ++n) g[n] = hin[so + n];
  const float* xrow = xdbl + (size_t)bk * cL * XSTR;
  int l0 = s * SEGLEN;
  float rv[44];
  if (fast) {
    for (int st = 0; st < SEGLEN; ++st) {
      int l = l0 + st;
      load_row(xrow + (size_t)l * XSTR, rv);
      float draw = dtb;
#pragma unroll
      for (int r = 0; r < cDTR; ++r) draw += rv[r] * wdt[r];
      float dt = softplusf(draw);
      float a1 = exp2f(dt * ac[0]);
      float ap = a1;
      float y = 0.f;
#pragma unroll
      for (int n = 0; n < cN; ++n) {
        g[n] *= ap;
        y += g[n] * rv[cDTR + cN + n];
        ap *= a1;
      }
      int v = scan_voxel(k, l);
      atomicAdd(&ysm[((size_t)b * cL + v) * cDI + d], y);
    }
  } else {
    for (int st = 0; st < SEGLEN; ++st) {
      int l = l0 + st;
      load_row(xrow + (size_t)l * XSTR, rv);
      float draw = dtb;
#pragma unroll
      for (int r = 0; r < cDTR; ++r) draw += rv[r] * wdt[r];
      float dt = softplusf(draw);
      float y = 0.f;
#pragma unroll
      for (int n = 0; n < cN; ++n) {
        float a = exp2f(dt * ac[n]);
        g[n] *= a;
        y += g[n] * rv[cDTR + cN + n];
      }
      int v = scan_voxel(k, l);
      atomicAdd(&ysm[((size_t)b * cL + v) * cDI + d], y);
    }
  }
}

// ---------- out_norm LN over merged ysm + silu(z) gate ----------
__global__ void __launch_bounds__(128) merge_kernel(
    const float* __restrict__ ysm, const float* __restrict__ z,
    const void* __restrict__ ong, const void* __restrict__ onb,
    const int* __restrict__ flg, float* __restrict__ yg) {
  int pf = flg[1];
  int bv = blockIdx.x;
  const float* yr = ysm + (size_t)bv * cDI;
  float vals[3]; float s1 = 0.f, s2 = 0.f;
#pragma unroll
  for (int i = 0; i < 3; ++i) {
    int d = threadIdx.x + i * 128;
    float x = yr[d];
    vals[i] = x; s1 += x; s2 += x * x;
  }
  blkreduce2<128>(s1, s2);
  float mean = s1 * (1.f / cDI);
  float var = s2 * (1.f / cDI) - mean * mean;
  float rstd = rsqrtf(var + 1e-6f);
  const float* zr = z + (size_t)bv * cDI;
  float* og = yg + (size_t)bv * cDI;
#pragma unroll
  for (int i = 0; i < 3; ++i) {
    int d = threadIdx.x + i * 128;
    float xn = (vals[i] - mean) * rstd * ldsel(ong, d, pf) + ldsel(onb, d, pf);
    og[d] = xn * siluf(zr[d]);
  }
}

}  // namespace

extern "C" void kernel_launch(void* const* d_in, const int* in_sizes, int n_in,
                              void* d_out, int out_size, void* d_ws, size_t ws_size,
                              hipStream_t stream) {
  (void)in_sizes; (void)n_in; (void)out_size; (void)ws_size;
  const void* x    = d_in[0];
  const void* text = d_in[1];
  const void* c1w  = d_in[2];
  const void* c1b  = d_in[3];
  const void* c2w  = d_in[4];
  const void* c2b  = d_in[5];
  const void* n1g  = d_in[6];
  const void* n1b  = d_in[7];
  const void* n2g  = d_in[8];
  const void* n2b  = d_in[9];
  const void* ipw  = d_in[10];
  const void* ipb  = d_in[11];
  const void* tpw  = d_in[12];
  const void* tpb  = d_in[13];
  const void* cvw  = d_in[14];
  const void* cvb  = d_in[15];
  const void* xpw  = d_in[16];
  const void* dtw  = d_in[17];
  const void* dtb  = d_in[18];
  const void* alog = d_in[19];
  const void* dsv  = d_in[20];
  const void* ong  = d_in[21];
  const void* onb  = d_in[22];
  const void* opw  = d_in[23];
  const void* f1w  = d_in[24];
  const void* f1b  = d_in[25];
  const void* f2w  = d_in[26];
  const void* f2b  = d_in[27];

  float* Wf = (float*)d_ws;

  // ---- slot arena (~125.9 MB); liveness as audited rounds 1-5 ----
  constexpr size_t oC  = 0;                              // 6,291,456
  constexpr size_t oD  = 6291456;                        // 3,145,728
  constexpr size_t oG  = 9437184;                        // 3,145,728
  constexpr size_t oA  = 12582912;                       // 6,291,456
  constexpr size_t oB  = 18874368;                       // 6,291,456
  constexpr size_t oE  = 25165824;                       // 3,145,728
  constexpr size_t oF  = 28311552;                       // 3,145,728
  constexpr size_t oCO = 31457280;                       // 768 (cond)
  constexpr size_t oFL = 31458048;                       // 4 ints (flags)
  // conv prep area (fp32): transposed weights + biases
  constexpr size_t oWCV = 31458052;                      // 27*384 = 10368
  constexpr size_t oBCV = 31468420;                      // 384
  constexpr size_t oW1  = 31468804;                      // 27*192 = 5184
  constexpr size_t oB1  = 31473988;                      // 192
  constexpr size_t oW2  = 31474180;                      // 5184
  constexpr size_t oB2  = 31479364;                      // 192 -> end 31479556 (~125.9MB)
  float* xc   = Wf + oC;
  float* xdbl = Wf + oD;
  float* xn   = Wf + oG;
  float* pend = Wf + oG;
  float* xi   = Wf + oA;
  float* ysm  = Wf + oA;
  float* x2   = Wf + oA;
  float* z    = Wf + oB;
  float* yg   = Wf + oB;
  float* x3   = Wf + oB;
  float* x1   = Wf + oE;
  float* hend = Wf + oF;
  float* xn2  = Wf + oF;
  float* cond = Wf + oCO;
  float* hbuf = Wf + oC;
  int*   flg  = (int*)(Wf + oFL);
  float* wcv = Wf + oWCV; float* bcv = Wf + oBCV;
  float* w1t = Wf + oW1;  float* b1t = Wf + oB1;
  float* w2t = Wf + oW2;  float* b2t = Wf + oB2;

  const int cpeBlocks = (cBL * cC / 4) / 256;     // 3072
  const int dwBlocks  = (cBL * cDI / 4) / 256;    // 6144

  // 0. dtype detection + conv weight prep
  hipLaunchKernelGGL(detect_kernel, dim3(1), dim3(256), 0, stream,
                     (const unsigned short*)x, (const unsigned short*)ipw, flg);
  hipLaunchKernelGGL(prep_kernel, dim3(85), dim3(256), 0, stream,
                     cvw, cvb, c1w, c1b, c2w, c2b, flg, wcv, bcv, w1t, b1t, w2t, b2t);
  // 1. x1 = x + cpe1(x)
  hipLaunchKernelGGL(cpe_kernel, dim3(cpeBlocks), dim3(256), 0, stream,
                     x, w1t, b1t, flg, 0, x1);
  // 2. xn = LN1(x1)
  hipLaunchKernelGGL(ln_kernel, dim3(cBL), dim3(256), 0, stream, x1, n1g, n1b, flg, xn, cC);
  // 3. cond
  hipLaunchKernelGGL(text_cond_kernel, dim3(cB), dim3(384), 0, stream, text, tpw, tpb, flg, cond);
  // 4. in_proj (MFMA): xn -> xi (+cond), z
  hipLaunchKernelGGL((gemm_mfma_kernel<0>), dim3(2 * cDI / 64, cBL / 128), dim3(256), 0, stream,
                     xn, ipw, 2 * cDI, cC, ipb, flg, cond, xi, z);
  // 5. xc = silu(dwconv(xi))
  hipLaunchKernelGGL(dwconv_silu_kernel, dim3(dwBlocks), dim3(256), 0, stream,
                     xi, wcv, bcv, xc);
  // 6. zero ysm
  hipLaunchKernelGGL(zero4_kernel, dim3(cBL * cDI / 4 / 256), dim3(256), 0, stream,
                     (float4*)ysm, cBL * cDI / 4);
  // 7. x_proj (MFMA, scatter to padded scan rows)
  hipLaunchKernelGGL((gemm_mfma_kernel<1>), dim3((cK * XROW + 63) / 64, cBL / 128), dim3(256), 0, stream,
                     xc, xpw, cK * XROW, cDI, (const void*)nullptr, flg,
                     (const float*)nullptr, xdbl, (float*)nullptr);
  // 8-10. chunked selective scan
  hipLaunchKernelGGL(scan1_kernel, dim3(cDI / 128, cB * cK * SEG), dim3(128), 0, stream,
                     xc, xdbl, dtw, dtb, alog, dsv, flg, ysm, hend, pend);
  hipLaunchKernelGGL(scan2_kernel, dim3(cB * cK * cDI * cN / 256), dim3(256), 0, stream,
                     hend, pend);
  hipLaunchKernelGGL(scan3_kernel, dim3(cDI / 128, cB * cK * SEG), dim3(128), 0, stream,
                     xdbl, dtw, dtb, alog, flg, hend, ysm);
  // 11. out_norm + gate
  hipLaunchKernelGGL(merge_kernel, dim3(cBL), dim3(128), 0, stream, ysm, z, ong, onb, flg, yg);
  // 12. out_proj + residual(x1) -> x2 (MFMA)
  hipLaunchKernelGGL((gemm_mfma_kernel<2>), dim3(cC / 64, cBL / 128), dim3(256), 0, stream,
                     yg, opw, cC, cDI, (const void*)nullptr, flg, x1, x2,
                     (float*)nullptr);
  // 13. x3 = x2 + cpe2(x2)  (flg[2]=1 -> fp32 input path)
  hipLaunchKernelGGL(cpe_kernel, dim3(cpeBlocks), dim3(256), 0, stream,
                     x2, w2t, b2t, flg, 2, x3);
  // 14. xn2 = LN2(x3)
  hipLaunchKernelGGL(ln_kernel, dim3(cBL), dim3(256), 0, stream, x3, n2g, n2b, flg, xn2, cC);
  // 15. fc1 + gelu -> hbuf (MFMA)
  hipLaunchKernelGGL((gemm_mfma_kernel<3>), dim3(cHID / 64, cBL / 128), dim3(256), 0, stream,
                     xn2, f1w, cHID, cC, f1b, flg, (const float*)nullptr, hbuf,
                     (float*)nullptr);
  // 16. fc2 + bias + residual(x3) -> d_out fp32 (MFMA)
  hipLaunchKernelGGL((gemm_mfma_kernel<4>), dim3(cC / 64, cBL / 128), dim3(256), 0, stream,
                     hbuf, f2w, cC, cHID, f2b, flg, x3, (float*)d_out,
                     (float*)nullptr);
}